// Round 3
// baseline (194.215 us; speedup 1.0000x reference)
//
#include <hip/hip_runtime.h>
#include <math.h>

#define H 1024
#define L 4096
#define V 29

__device__ inline float waveReduceSum(float v) {
    #pragma unroll
    for (int off = 32; off > 0; off >>= 1)
        v += __shfl_down(v, off, 64);
    return v;
}

// K1: blocks 0..1023  -> attn rows 4b..4b+3: e=exp(logit), blocksum[b]
//     blocks 1024..2047 -> W_hh rows: hhg[r] = h0.W_hh[r] + b_ih[r] + b_hh[r]
//     block 0 also zeroes attn_acc and the fan-in counter.
__global__ __launch_bounds__(256) void k1_logits_hh(
    const int* __restrict__ tok, const float* __restrict__ h0,
    const float* __restrict__ emb, const float* __restrict__ attn_W,
    const float* __restrict__ attn_b, const float* __restrict__ W_hh,
    const float* __restrict__ b_ih, const float* __restrict__ b_hh,
    float* __restrict__ e_ws, float* __restrict__ blocksum,
    float* __restrict__ hhg, float* __restrict__ attn_acc,
    unsigned int* __restrict__ ctr)
{
    __shared__ float4 sbuf[512];
    __shared__ float sred[4];
    const int tid = threadIdx.x, bid = blockIdx.x;
    const int wave = tid >> 6, lane = tid & 63;

    if (bid == 0) {
        ((float4*)attn_acc)[tid] = make_float4(0.f, 0.f, 0.f, 0.f);
        if (tid == 0) *ctr = 0u;
    }

    if (bid < 1024) {
        const int t = tok[0];
        sbuf[tid]       = ((const float4*)(emb + (size_t)t * H))[tid];
        sbuf[256 + tid] = ((const float4*)h0)[tid];
        __syncthreads();
        const int row = bid * 4 + wave;
        const float4* wr = (const float4*)(attn_W + (size_t)row * (2 * H));
        float acc = 0.f;
        #pragma unroll
        for (int k = 0; k < 8; ++k) {
            float4 a = wr[k * 64 + lane];
            float4 b = sbuf[k * 64 + lane];
            acc += a.x * b.x + a.y * b.y + a.z * b.z + a.w * b.w;
        }
        acc = waveReduceSum(acc);
        if (lane == 0) {
            float e = __expf(acc + attn_b[row]);   // |logit| <~ 5: safe w/o max
            e_ws[row] = e;
            sred[wave] = e;
        }
        __syncthreads();
        if (tid == 0) blocksum[bid] = sred[0] + sred[1] + sred[2] + sred[3];
    } else {
        sbuf[tid] = ((const float4*)h0)[tid];
        __syncthreads();
        const int row = (bid - 1024) * 4 + wave;
        const float4* wr = (const float4*)(W_hh + (size_t)row * H);
        float acc = 0.f;
        #pragma unroll
        for (int k = 0; k < 4; ++k) {
            float4 a = wr[k * 64 + lane];
            float4 b = sbuf[k * 64 + lane];
            acc += a.x * b.x + a.y * b.y + a.z * b.z + a.w * b.w;
        }
        acc = waveReduceSum(acc);
        if (lane == 0) hhg[row] = acc + b_ih[row] + b_hh[row];
    }
}

// K2: redundant denom reduce (1024 partials, L2-hot) + weighted encoder sum
//     + normalized attn_weights out. 256 blocks x 16 rows.
__global__ __launch_bounds__(256) void k2_apply(
    const float* __restrict__ e_ws, const float* __restrict__ blocksum,
    const float* __restrict__ enc, float* __restrict__ attn_acc,
    float* __restrict__ attn_w_out)
{
    __shared__ float sred[4];
    const int tid = threadIdx.x, bid = blockIdx.x;
    const int wave = tid >> 6, lane = tid & 63;

    float4 bs = ((const float4*)blocksum)[tid];
    float s = bs.x + bs.y + bs.z + bs.w;
    s = waveReduceSum(s);
    if (lane == 0) sred[wave] = s;
    __syncthreads();
    const float inv = 1.f / (sred[0] + sred[1] + sred[2] + sred[3]);

    float4 acc4 = make_float4(0.f, 0.f, 0.f, 0.f);
    #pragma unroll 4
    for (int r = 0; r < 16; ++r) {
        const int l = bid * 16 + r;
        const float w = e_ws[l] * inv;
        float4 ev = ((const float4*)(enc + (size_t)l * H))[tid];
        acc4.x += w * ev.x; acc4.y += w * ev.y;
        acc4.z += w * ev.z; acc4.w += w * ev.w;
    }
    if (tid < 16) attn_w_out[bid * 16 + tid] = e_ws[bid * 16 + tid] * inv;
    const int c = tid * 4;
    atomicAdd(&attn_acc[c + 0], acc4.x);
    atomicAdd(&attn_acc[c + 1], acc4.y);
    atomicAdd(&attn_acc[c + 2], acc4.z);
    atomicAdd(&attn_acc[c + 3], acc4.w);
}

// K3: x[row] = relu([emb, attn_applied] . comb_W[row] + comb_b[row])
__global__ __launch_bounds__(256) void k3_combine(
    const int* __restrict__ tok, const float* __restrict__ emb,
    const float* __restrict__ attn_acc, const float* __restrict__ comb_W,
    const float* __restrict__ comb_b, float* __restrict__ xbuf)
{
    __shared__ float4 sbuf[512];
    const int tid = threadIdx.x, bid = blockIdx.x;
    const int wave = tid >> 6, lane = tid & 63;
    const int t = tok[0];
    sbuf[tid]       = ((const float4*)(emb + (size_t)t * H))[tid];
    sbuf[256 + tid] = ((const float4*)attn_acc)[tid];
    __syncthreads();
    const int row = bid * 4 + wave;                 // 256 blocks -> 1024 rows
    const float4* wr = (const float4*)(comb_W + (size_t)row * (2 * H));
    float acc = 0.f;
    #pragma unroll
    for (int k = 0; k < 8; ++k) {
        float4 a = wr[k * 64 + lane];
        float4 b = sbuf[k * 64 + lane];
        acc += a.x * b.x + a.y * b.y + a.z * b.z + a.w * b.w;
    }
    acc = waveReduceSum(acc);
    if (lane == 0) xbuf[row] = fmaxf(acc + comb_b[row], 0.f);
}

// K4: per wave: all 4 gate dots for one hidden unit -> LSTM elementwise ->
//     h_new/c_new out. Last-finishing block does out-proj + log_softmax.
__global__ __launch_bounds__(256) void k4_gates_final(
    const float* __restrict__ xbuf, const float* __restrict__ c0,
    const float* __restrict__ W_ih, const float* __restrict__ hhg,
    const float* __restrict__ out_W, const float* __restrict__ out_b,
    float* __restrict__ hnew_ws, unsigned int* __restrict__ ctr,
    float* __restrict__ out)
{
    __shared__ float4 sx[256];
    __shared__ float logit[32];
    __shared__ bool amLast;
    const int tid = threadIdx.x, bid = blockIdx.x;  // 256 blocks
    const int wave = tid >> 6, lane = tid & 63;
    sx[tid] = ((const float4*)xbuf)[tid];
    __syncthreads();

    const int h = bid * 4 + wave;                   // hidden unit
    const float4* wi = (const float4*)(W_ih + (size_t)h * H);
    const float4* wf = (const float4*)(W_ih + (size_t)(H + h) * H);
    const float4* wg = (const float4*)(W_ih + (size_t)(2 * H + h) * H);
    const float4* wo = (const float4*)(W_ih + (size_t)(3 * H + h) * H);
    float ai = 0.f, af = 0.f, ag = 0.f, ao = 0.f;
    #pragma unroll
    for (int k = 0; k < 4; ++k) {
        float4 b = sx[k * 64 + lane];
        float4 a = wi[k * 64 + lane]; ai += a.x*b.x + a.y*b.y + a.z*b.z + a.w*b.w;
        float4 f = wf[k * 64 + lane]; af += f.x*b.x + f.y*b.y + f.z*b.z + f.w*b.w;
        float4 g = wg[k * 64 + lane]; ag += g.x*b.x + g.y*b.y + g.z*b.z + g.w*b.w;
        float4 o = wo[k * 64 + lane]; ao += o.x*b.x + o.y*b.y + o.z*b.z + o.w*b.w;
    }
    ai = waveReduceSum(ai); af = waveReduceSum(af);
    ag = waveReduceSum(ag); ao = waveReduceSum(ao);
    if (lane == 0) {
        const float gi = ai + hhg[h];
        const float gf = af + hhg[H + h];
        const float gg = ag + hhg[2 * H + h];
        const float go = ao + hhg[3 * H + h];
        const float c  = c0[h];
        const float si = 1.f / (1.f + __expf(-gi));
        const float sf = 1.f / (1.f + __expf(-gf));
        const float so = 1.f / (1.f + __expf(-go));
        const float cn = sf * c + si * tanhf(gg);
        const float hn = so * tanhf(cn);
        out[V + h]     = hn;
        out[V + H + h] = cn;
        hnew_ws[h]     = hn;
    }

    // fan-in: last block to finish does the tiny output projection
    __threadfence();
    __syncthreads();
    if (tid == 0) amLast = (atomicAdd(ctr, 1u) == 255u);
    __syncthreads();
    if (amLast) {
        __threadfence();
        float* hn_l = (float*)sx;                   // reuse LDS, 1024 floats
        #pragma unroll
        for (int j = 0; j < 4; ++j) hn_l[tid + j * 256] = hnew_ws[tid + j * 256];
        __syncthreads();
        for (int v = wave; v < V; v += 4) {
            const float4* wr = (const float4*)(out_W + (size_t)v * H);
            float acc = 0.f;
            #pragma unroll
            for (int k = 0; k < 4; ++k) {
                float4 a = wr[k * 64 + lane];
                float4 b = ((const float4*)hn_l)[k * 64 + lane];
                acc += a.x * b.x + a.y * b.y + a.z * b.z + a.w * b.w;
            }
            acc = waveReduceSum(acc);
            if (lane == 0) logit[v] = acc + out_b[v];
        }
        __syncthreads();
        if (tid < 64) {
            const float val = (tid < V) ? logit[tid] : -3.4e38f;
            float m = val;
            #pragma unroll
            for (int off = 32; off > 0; off >>= 1)
                m = fmaxf(m, __shfl_down(m, off, 64));
            m = __shfl(m, 0, 64);
            float e = (tid < V) ? __expf(val - m) : 0.f;
            float s = e;
            #pragma unroll
            for (int off = 32; off > 0; off >>= 1)
                s += __shfl_down(s, off, 64);
            s = __shfl(s, 0, 64);
            if (tid < V) out[tid] = val - m - logf(s);
        }
    }
}

extern "C" void kernel_launch(void* const* d_in, const int* in_sizes, int n_in,
                              void* d_out, int out_size, void* d_ws, size_t ws_size,
                              hipStream_t stream) {
    const int*   tok    = (const int*)  d_in[0];
    const float* h0     = (const float*)d_in[1];
    const float* c0     = (const float*)d_in[2];
    const float* enc    = (const float*)d_in[3];
    const float* emb    = (const float*)d_in[4];
    const float* attn_W = (const float*)d_in[5];
    const float* attn_b = (const float*)d_in[6];
    const float* comb_W = (const float*)d_in[7];
    const float* comb_b = (const float*)d_in[8];
    const float* W_ih   = (const float*)d_in[9];
    const float* W_hh   = (const float*)d_in[10];
    const float* b_ih   = (const float*)d_in[11];
    const float* b_hh   = (const float*)d_in[12];
    const float* out_W  = (const float*)d_in[13];
    const float* out_b  = (const float*)d_in[14];

    float* out = (float*)d_out;
    float* ws  = (float*)d_ws;
    float* e_ws     = ws;                   // 4096
    float* blocksum = ws + 4096;            // 1024
    float* hhg      = ws + 5120;            // 4096
    float* attn_acc = ws + 9216;            // 1024
    float* xbuf     = ws + 10240;           // 1024
    float* hnew_ws  = ws + 11264;           // 1024
    unsigned int* ctr = (unsigned int*)(ws + 12288);
    float* attn_w_out = out + V + 2 * H;    // attn_weights section

    k1_logits_hh<<<2048, 256, 0, stream>>>(tok, h0, emb, attn_W, attn_b,
                                           W_hh, b_ih, b_hh,
                                           e_ws, blocksum, hhg, attn_acc, ctr);
    k2_apply<<<256, 256, 0, stream>>>(e_ws, blocksum, enc, attn_acc, attn_w_out);
    k3_combine<<<256, 256, 0, stream>>>(tok, emb, attn_acc, comb_W, comb_b, xbuf);
    k4_gates_final<<<256, 256, 0, stream>>>(xbuf, c0, W_ih, hhg,
                                            out_W, out_b, hnew_ws, ctr, out);
}